// Round 13
// baseline (478.382 us; speedup 1.0000x reference)
//
#include <hip/hip_runtime.h>
#include <hip/hip_bf16.h>
#include <cstdint>

#define DIM 32
#define OUTD 128
#define B_PART 256     // blocks in hist/partition passes
#define BSHIFT 9       // bucket = 512 nodes

// ---------------- index-load helper (int32 vs int64 inputs) ----------------
__device__ __forceinline__ int load_idx(const void* p, long long i, int is64) {
    if (is64) return (int)((const long long*)p)[i];
    return ((const int*)p)[i];
}

// Detect whether integer inputs are int64 (8B) or int32 (4B).
__global__ void detect_dtype_kernel(const void* __restrict__ edge, int* __restrict__ flag, int n_nodes) {
    __shared__ int cnt;
    if (threadIdx.x == 0) cnt = 0;
    __syncthreads();
    long long v = ((const long long*)edge)[threadIdx.x];
    int ok = (v >= 0 && v < (long long)n_nodes) ? 1 : 0;
    atomicAdd(&cnt, ok);
    __syncthreads();
    if (threadIdx.x == 0) *flag = (cnt > 128) ? 1 : 0;
}

// ---- pass 1: per-(bucket, block) histogram of destination buckets ----
__global__ __launch_bounds__(256) void hist_kernel(const void* __restrict__ edge,
                                                   const int* __restrict__ flag,
                                                   int* __restrict__ histT,
                                                   int eN, int NB, int chunk) {
    __shared__ int sh[256];
    int t = threadIdx.x, bid = blockIdx.x;
    sh[t] = 0;
    __syncthreads();
    int f = *flag;
    int s = bid * chunk, e = min(eN, s + chunk);
    for (int i = s + t; i < e; i += 256) {
        int c = load_idx(edge, (long long)eN + i, f);
        atomicAdd(&sh[c >> BSHIFT], 1);
    }
    __syncthreads();
    if (t < NB) histT[t * B_PART + bid] = sh[t];   // bucket-major layout
}

// ---- generic hierarchical exclusive scan over M ints (A: block sums) ----
__global__ __launch_bounds__(512) void scanA_kernel(const int* __restrict__ a,
                                                    int* __restrict__ sums, int M) {
    __shared__ int red[512];
    int i = blockIdx.x * 512 + threadIdx.x;
    int v = (i < M) ? a[i] : 0;
    red[threadIdx.x] = v;
    __syncthreads();
    for (int off = 256; off > 0; off >>= 1) {
        if (threadIdx.x < off) red[threadIdx.x] += red[threadIdx.x + off];
        __syncthreads();
    }
    if (threadIdx.x == 0) sums[blockIdx.x] = red[0];
}

// ---- B: exclusive scan of block sums (<=1024) ----
__global__ __launch_bounds__(1024) void scanB_kernel(int* __restrict__ sums, int nb) {
    __shared__ int part[1024];
    int t = threadIdx.x;
    int v = (t < nb) ? sums[t] : 0;
    part[t] = v;
    __syncthreads();
    for (int off = 1; off < 1024; off <<= 1) {
        int u = (t >= off) ? part[t - off] : 0;
        __syncthreads();
        part[t] += u;
        __syncthreads();
    }
    if (t < nb) sums[t] = part[t] - v;
}

// ---- C: apply (in-place exclusive scan) ----
__global__ __launch_bounds__(512) void scanC_kernel(int* __restrict__ a,
                                                    const int* __restrict__ sums, int M) {
    __shared__ int part[512];
    int t = threadIdx.x;
    int i = blockIdx.x * 512 + t;
    int v = (i < M) ? a[i] : 0;
    part[t] = v;
    __syncthreads();
    for (int off = 1; off < 512; off <<= 1) {
        int u = (t >= off) ? part[t - off] : 0;
        __syncthreads();
        part[t] += u;
        __syncthreads();
    }
    if (i < M) a[i] = part[t] - v + sums[blockIdx.x];
}

// ---- pass 2: partition edges into bucket runs; pack (r | local_c<<23) in 4B ----
__global__ __launch_bounds__(256) void partition_kernel(const void* __restrict__ edge,
                                                        const int* __restrict__ flag,
                                                        const int* __restrict__ offs,
                                                        unsigned int* __restrict__ pairs,
                                                        int eN, int NB, int chunk) {
    __shared__ int cur[256];
    int t = threadIdx.x, bid = blockIdx.x;
    if (t < NB) cur[t] = offs[t * B_PART + bid];
    __syncthreads();
    int f = *flag;
    int s = bid * chunk, e = min(eN, s + chunk);
    for (int i = s + t; i < e; i += 256) {
        int r = load_idx(edge, i, f);
        int c = load_idx(edge, (long long)eN + i, f);
        int slot = atomicAdd(&cur[c >> BSHIFT], 1);
        pairs[slot] = (unsigned)r | ((unsigned)(c & 511) << 23);
    }
}

// ---- pass 3: per-bucket CSR build (counting sort by lc) + within-bucket degree sort ----
// order[base+rank] = node, ranked by ascending degree within the bucket; conv waves
// then process near-equal-degree nodes -> balanced waves, uniform guard branches.
__global__ __launch_bounds__(256) void bucket_fill_kernel(const unsigned int* __restrict__ pairs,
                                                          const int* __restrict__ offs,
                                                          int* __restrict__ rowptr,
                                                          float* __restrict__ dinv,
                                                          int* __restrict__ csr_src,
                                                          int* __restrict__ order,
                                                          int n, int eN, int NB) {
    __shared__ int cnt2[512];
    __shared__ int psum[256];
    __shared__ int dh[128];
    int t = threadIdx.x, b = blockIdx.x;
    int base = b << BSHIFT;
    int nLocal = min(512, n - base);
    int s = offs[b * B_PART];
    int e = (b + 1 < NB) ? offs[(b + 1) * B_PART] : eN;
    cnt2[t] = 0;
    cnt2[t + 256] = 0;
    __syncthreads();
    for (int i = s + t; i < e; i += 256) atomicAdd(&cnt2[pairs[i] >> 23], 1);
    __syncthreads();
    int a0 = cnt2[2 * t], a1 = cnt2[2 * t + 1];
    psum[t] = a0 + a1;
    __syncthreads();
    for (int off = 1; off < 256; off <<= 1) {
        int u = (t >= off) ? psum[t - off] : 0;
        __syncthreads();
        psum[t] += u;
        __syncthreads();
    }
    int ex = psum[t] - (a0 + a1);
    __syncthreads();
    cnt2[2 * t] = ex;
    cnt2[2 * t + 1] = ex + a0;
    __syncthreads();
    for (int j = t; j < nLocal; j += 256) {
        int st = cnt2[j];
        int en = (j < 511) ? cnt2[j + 1] : (e - s);
        rowptr[base + j] = s + st;
        dinv[base + j] = rsqrtf((float)(en - st + 1));
    }
    if (b == NB - 1 && t == 0) rowptr[n] = eN;
    // ---- degree counting sort (reads cnt2 before placement mutates it) ----
    if (t < 128) dh[t] = 0;
    __syncthreads();
    for (int j = t; j < nLocal; j += 256) {
        int st = cnt2[j];
        int en = (j < 511) ? cnt2[j + 1] : (e - s);
        atomicAdd(&dh[min(en - st, 127)], 1);
    }
    __syncthreads();
    if (t == 0) {
        int run = 0;
        for (int d = 0; d < 128; ++d) { int c = dh[d]; dh[d] = run; run += c; }
    }
    __syncthreads();
    for (int j = t; j < nLocal; j += 256) {
        int st = cnt2[j];
        int en = (j < 511) ? cnt2[j + 1] : (e - s);
        int rank = atomicAdd(&dh[min(en - st, 127)], 1);
        order[base + rank] = base + j;
    }
    __syncthreads();
    // ---- placement (mutates cnt2) ----
    for (int i = s + t; i < e; i += 256) {
        unsigned p = pairs[i];
        int lc = (int)(p >> 23);
        int r = (int)(p & 0x7FFFFFu);
        int slot = atomicAdd(&cnt2[lc], 1);
        csr_src[s + slot] = r;
    }
}

// ---- per-row biased-uint8 quantization of v = dinv[node]*x : qu = rint(v*127/m)+128 ----
__global__ __launch_bounds__(256) void prescale_q_kernel(const float* __restrict__ x,
                                                         const float* __restrict__ dinv,
                                                         unsigned char* __restrict__ q,
                                                         float* __restrict__ scale, int n) {
    int t = threadIdx.x;
    int k = t & 31;
    int g = blockIdx.x * 8 + (t >> 5);
    if (g >= n) return;
    float v = dinv[g] * x[(size_t)g * 32 + k];
    float m = fabsf(v);
    #pragma unroll
    for (int w = 1; w < 32; w <<= 1) m = fmaxf(m, __shfl_xor(m, w, 32));
    float inv = (m > 0.f) ? 127.f / m : 0.f;
    float qf = fminf(127.f, fmaxf(-127.f, rintf(v * inv)));
    q[(size_t)g * 32 + k] = (unsigned char)(int)(qf + 128.f);
    if (k == 0) scale[g] = m * (1.f / 127.f);
}

// Fused GCN conv, two-phase, degree-ordered nodes, W in LDS (low VGPR -> occupancy):
//  Phase 1 (8 lanes/node): chunk-32 upfront loads + subtile guards (wave-uniform after
//  degree sort). Phase 2 per wave: mini-GEMM from LDS W, residual/relu/quant.
template <int HAS_RES, int WRITE_F32, int WRITE_Q>
__global__ __launch_bounds__(256) void fused_conv_kernel(const unsigned char* __restrict__ q,
                                                         const float* __restrict__ scale,
                                                         const int* __restrict__ rowptr,
                                                         const int* __restrict__ src,
                                                         const int* __restrict__ order,
                                                         const float* __restrict__ dinv,
                                                         const float* __restrict__ W,
                                                         const float* __restrict__ bias,
                                                         const float* __restrict__ res,
                                                         float* __restrict__ out,
                                                         unsigned char* __restrict__ q_out,
                                                         float* __restrict__ scale_out,
                                                         int n) {
    __shared__ float sW[1024];
    __shared__ float aggL[32 * 36];
    int t = threadIdx.x;
    int k32 = t & 31;
    for (int i = t; i < 1024; i += 256) sW[i] = W[i];
    __syncthreads();                      // only block-wide sync (sW ready)

    // ---------- phase 1: aggregation ----------
    int slot = t >> 3;                    // node slot 0..31 (wave w owns slots 8w..8w+7)
    int m = t & 7;                        // feature quad 4m..4m+3
    int gi = blockIdx.x * 32 + slot;
    if (gi < n) {
        int g = order[gi];
        float scg = scale[g];
        unsigned qw = *(const unsigned*)(q + (size_t)g * 32 + m * 4);
        float acc0 = (float)((qw      ) & 0xFFu) * scg;
        float acc1 = (float)((qw >>  8) & 0xFFu) * scg;
        float acc2 = (float)((qw >> 16) & 0xFFu) * scg;
        float acc3 = (float)((qw >> 24)        ) * scg;
        float accs = scg;
        int s = rowptr[g], e = rowptr[g + 1];
        int last = e - 1;
        for (int p = s; p < e; p += 32) {
            int i0 = p + m;
            int sv0 = src[min(i0,      last)];
            int sv1 = src[min(i0 + 8,  last)];
            int sv2 = src[min(i0 + 16, last)];
            int sv3 = src[min(i0 + 24, last)];
            float sg0 = scale[sv0];
            float sg1 = scale[sv1];
            float sg2 = scale[sv2];
            float sg3 = scale[sv3];
            sg0 = (i0      < e) ? sg0 : 0.f;
            sg1 = (i0 + 8  < e) ? sg1 : 0.f;
            sg2 = (i0 + 16 < e) ? sg2 : 0.f;
            sg3 = (i0 + 24 < e) ? sg3 : 0.f;
            #pragma unroll
            for (int st = 0; st < 4; ++st) {
                int svx = (st == 0) ? sv0 : (st == 1) ? sv1 : (st == 2) ? sv2 : sv3;
                float sgx = (st == 0) ? sg0 : (st == 1) ? sg1 : (st == 2) ? sg2 : sg3;
                if (p + st * 8 < e) {      // wave-uniform after degree sort
                    #pragma unroll
                    for (int jj = 0; jj < 8; ++jj) {
                        int sr = __shfl(svx, jj, 8);
                        float sc = __shfl(sgx, jj, 8);
                        unsigned w4 = *(const unsigned*)(q + (size_t)sr * 32 + m * 4);
                        acc0 = fmaf((float)((w4      ) & 0xFFu), sc, acc0);
                        acc1 = fmaf((float)((w4 >>  8) & 0xFFu), sc, acc1);
                        acc2 = fmaf((float)((w4 >> 16) & 0xFFu), sc, acc2);
                        acc3 = fmaf((float)((w4 >> 24)        ), sc, acc3);
                        accs += sc;
                    }
                }
            }
        }
        float di = dinv[g];
        float corr = 128.f * accs;
        aggL[slot * 36 + m * 4 + 0] = di * (acc0 - corr);
        aggL[slot * 36 + m * 4 + 1] = di * (acc1 - corr);
        aggL[slot * 36 + m * 4 + 2] = di * (acc2 - corr);
        aggL[slot * 36 + m * 4 + 3] = di * (acc3 - corr);
    }
    __builtin_amdgcn_wave_barrier();      // same-wave LDS ordering

    // ---------- phase 2: per-wave mini-GEMM epilogue ----------
    float bk = bias[k32];
    int wv = t >> 6;                      // wave 0..3
    int h = (t >> 5) & 1;                 // half-wave group
    #pragma unroll
    for (int r = 0; r < 4; ++r) {
        int slot2 = wv * 8 + r * 2 + h;
        int g2i = blockIdx.x * 32 + slot2;
        if (g2i < n) {
            int g2 = order[g2i];
            float agg = aggL[slot2 * 36 + k32];
            float o = bk;
            #pragma unroll
            for (int j = 0; j < 32; ++j) {
                float aj = __shfl(agg, j, 32);
                o = fmaf(aj, sW[j * 32 + k32], o);
            }
            if (HAS_RES) o += res[(size_t)g2 * 32 + k32];
            o = fmaxf(o, 0.f);
            if (WRITE_F32) out[(size_t)g2 * 32 + k32] = o;
            if (WRITE_Q) {
                float v = dinv[g2] * o;
                float mx = fabsf(v);
                #pragma unroll
                for (int w = 1; w < 32; w <<= 1) mx = fmaxf(mx, __shfl_xor(mx, w, 32));
                float inv = (mx > 0.f) ? 127.f / mx : 0.f;
                float qf = fminf(127.f, fmaxf(-127.f, rintf(v * inv)));
                q_out[(size_t)g2 * 32 + k32] = (unsigned char)(int)(qf + 128.f);
                if (k32 == 0) scale_out[g2] = mx * (1.f / 127.f);
            }
        }
    }
}

// one block per graph: mean-pool (batch is sorted -> binary search range) + 32->128 FC
__global__ __launch_bounds__(128) void pool_fc_kernel(const float* __restrict__ h,
                                                      const void* __restrict__ batch,
                                                      const int* __restrict__ flag,
                                                      const float* __restrict__ Wl,
                                                      const float* __restrict__ bl,
                                                      float* __restrict__ out, int n) {
    __shared__ float red[4][32];
    __shared__ float sp[32];
    __shared__ int srange[2];
    int g = blockIdx.x;
    int t = threadIdx.x;
    int f = *flag;
    if (t < 2) {
        int target = g + t;
        int lo = 0, hi = n;
        while (lo < hi) {
            int mid = (lo + hi) >> 1;
            int v = load_idx(batch, mid, f);
            if (v < target) lo = mid + 1; else hi = mid;
        }
        srange[t] = lo;
    }
    __syncthreads();
    int s = srange[0], e = srange[1];
    int gi = t >> 5, k = t & 31;
    float acc = 0.f;
    for (int i = s + gi; i < e; i += 4) acc += h[(size_t)i * 32 + k];
    red[gi][k] = acc;
    __syncthreads();
    if (gi == 0) {
        float v = red[0][k] + red[1][k] + red[2][k] + red[3][k];
        sp[k] = v / fmaxf((float)(e - s), 1.0f);
    }
    __syncthreads();
    float val = bl[t];
    #pragma unroll
    for (int j = 0; j < 32; ++j) val = fmaf(sp[j], Wl[j * 128 + t], val);
    out[(size_t)g * 128 + t] = val;
}

extern "C" void kernel_launch(void* const* d_in, const int* in_sizes, int n_in,
                              void* d_out, int out_size, void* d_ws, size_t ws_size,
                              hipStream_t stream) {
    const float* x = (const float*)d_in[0];
    const void* edge = d_in[1];
    const void* batch = d_in[2];
    const float* W[6] = {(const float*)d_in[3], (const float*)d_in[5],
                         (const float*)d_in[7], (const float*)d_in[9],
                         (const float*)d_in[11], (const float*)d_in[13]};
    const float* B[6] = {(const float*)d_in[4], (const float*)d_in[6],
                         (const float*)d_in[8], (const float*)d_in[10],
                         (const float*)d_in[12], (const float*)d_in[14]};
    const float* Wl = (const float*)d_in[15];
    const float* bl = (const float*)d_in[16];
    float* out = (float*)d_out;

    int n = in_sizes[0] / DIM;      // 100000 nodes
    int eN = in_sizes[1] / 2;       // 3200000 edges
    int gN = out_size / OUTD;       // 8192 graphs

    int NB = (n + 511) >> BSHIFT;   // 196 buckets (<=256 for n<=131072)
    int M = NB * B_PART;            // hist matrix size
    int chunk = (eN + B_PART - 1) / B_PART;
    int nbA = (M + 511) / 512;

    char* ws = (char*)d_ws;
    size_t off = 0;
    auto alloc = [&](size_t bytes) {
        void* p = ws + off;
        off += (bytes + 255) & ~(size_t)255;
        return p;
    };
    int* flag      = (int*)alloc(4);
    int* offs      = (int*)alloc((size_t)B_PART * 256 * 4);   // hist/offsets (bucket-major)
    int* sumsA     = (int*)alloc(1024 * 4);
    int* rowptr    = (int*)alloc((size_t)(n + 1) * 4);
    float* dinv    = (float*)alloc((size_t)n * 4);
    int* csr_src   = (int*)alloc((size_t)eN * 4);
    int* order     = (int*)alloc((size_t)n * 4);
    float* bufB    = (float*)alloc((size_t)n * DIM * 4);
    unsigned char* qX = (unsigned char*)alloc((size_t)n * DIM);
    unsigned char* qA = (unsigned char*)alloc((size_t)n * DIM);
    unsigned char* qB = (unsigned char*)alloc((size_t)n * DIM);
    unsigned char* qC = (unsigned char*)alloc((size_t)n * DIM);
    float* scX     = (float*)alloc((size_t)n * 4);
    float* scA     = (float*)alloc((size_t)n * 4);
    float* scB     = (float*)alloc((size_t)n * 4);
    float* scC     = (float*)alloc((size_t)n * 4);
    size_t pairsB  = (size_t)eN * 4;
    size_t bufCB   = (size_t)n * DIM * 4;
    void* shared0  = alloc(pairsB > bufCB ? pairsB : bufCB);  // pairs, later bufC
    unsigned int* pairs = (unsigned int*)shared0;
    float* bufC    = (float*)shared0;

    detect_dtype_kernel<<<1, 256, 0, stream>>>(edge, flag, n);
    hist_kernel<<<B_PART, 256, 0, stream>>>(edge, flag, offs, eN, NB, chunk);
    scanA_kernel<<<nbA, 512, 0, stream>>>(offs, sumsA, M);
    scanB_kernel<<<1, 1024, 0, stream>>>(sumsA, nbA);
    scanC_kernel<<<nbA, 512, 0, stream>>>(offs, sumsA, M);
    partition_kernel<<<B_PART, 256, 0, stream>>>(edge, flag, offs, pairs, eN, NB, chunk);
    bucket_fill_kernel<<<NB, 256, 0, stream>>>(pairs, offs, rowptr, dinv, csr_src, order, n, eN, NB);

    int ab8 = (n + 7) / 8;
    prescale_q_kernel<<<ab8, 256, 0, stream>>>(x, dinv, qX, scX, n);

    int ab = (n + 31) / 32;   // conv grid: 32 nodes/block

    // Res-block 1: x --(c0)--> qA --(c1)--> bufB(+qB)
    fused_conv_kernel<0, 0, 1><<<ab, 256, 0, stream>>>(qX, scX, rowptr, csr_src, order, dinv, W[0], B[0], nullptr, nullptr, qA, scA, n);
    fused_conv_kernel<1, 1, 1><<<ab, 256, 0, stream>>>(qA, scA, rowptr, csr_src, order, dinv, W[1], B[1], x,       bufB,    qB, scB, n);
    // Res-block 2: bufB --(c2)--> qA --(c3)--> bufC(+qC)   (pairs dead now)
    fused_conv_kernel<0, 0, 1><<<ab, 256, 0, stream>>>(qB, scB, rowptr, csr_src, order, dinv, W[2], B[2], nullptr, nullptr, qA, scA, n);
    fused_conv_kernel<1, 1, 1><<<ab, 256, 0, stream>>>(qA, scA, rowptr, csr_src, order, dinv, W[3], B[3], bufB,    bufC,    qC, scC, n);
    // Res-block 3: bufC --(c4)--> qA --(c5)--> bufB (final, f32 only)
    fused_conv_kernel<0, 0, 1><<<ab, 256, 0, stream>>>(qC, scC, rowptr, csr_src, order, dinv, W[4], B[4], nullptr, nullptr, qA, scA, n);
    fused_conv_kernel<1, 1, 0><<<ab, 256, 0, stream>>>(qA, scA, rowptr, csr_src, order, dinv, W[5], B[5], bufC,    bufB,    nullptr, nullptr, n);

    pool_fc_kernel<<<gN, 128, 0, stream>>>(bufB, batch, flag, Wl, bl, out, n);
}

// Round 14
// 436.292 us; speedup vs baseline: 1.0965x; 1.0965x over previous
//
#include <hip/hip_runtime.h>
#include <hip/hip_bf16.h>
#include <cstdint>

#define DIM 32
#define OUTD 128
#define B_PART 256     // blocks in hist/partition passes
#define BSHIFT 9       // bucket = 512 nodes

// ---------------- index-load helper (int32 vs int64 inputs) ----------------
__device__ __forceinline__ int load_idx(const void* p, long long i, int is64) {
    if (is64) return (int)((const long long*)p)[i];
    return ((const int*)p)[i];
}

// Detect whether integer inputs are int64 (8B) or int32 (4B).
__global__ void detect_dtype_kernel(const void* __restrict__ edge, int* __restrict__ flag, int n_nodes) {
    __shared__ int cnt;
    if (threadIdx.x == 0) cnt = 0;
    __syncthreads();
    long long v = ((const long long*)edge)[threadIdx.x];
    int ok = (v >= 0 && v < (long long)n_nodes) ? 1 : 0;
    atomicAdd(&cnt, ok);
    __syncthreads();
    if (threadIdx.x == 0) *flag = (cnt > 128) ? 1 : 0;
}

// ---- pass 1: per-(bucket, block) histogram of destination buckets ----
__global__ __launch_bounds__(256) void hist_kernel(const void* __restrict__ edge,
                                                   const int* __restrict__ flag,
                                                   int* __restrict__ histT,
                                                   int eN, int NB, int chunk) {
    __shared__ int sh[256];
    int t = threadIdx.x, bid = blockIdx.x;
    sh[t] = 0;
    __syncthreads();
    int f = *flag;
    int s = bid * chunk, e = min(eN, s + chunk);
    for (int i = s + t; i < e; i += 256) {
        int c = load_idx(edge, (long long)eN + i, f);
        atomicAdd(&sh[c >> BSHIFT], 1);
    }
    __syncthreads();
    if (t < NB) histT[t * B_PART + bid] = sh[t];   // bucket-major layout
}

// ---- generic hierarchical exclusive scan over M ints (A: block sums) ----
__global__ __launch_bounds__(512) void scanA_kernel(const int* __restrict__ a,
                                                    int* __restrict__ sums, int M) {
    __shared__ int red[512];
    int i = blockIdx.x * 512 + threadIdx.x;
    int v = (i < M) ? a[i] : 0;
    red[threadIdx.x] = v;
    __syncthreads();
    for (int off = 256; off > 0; off >>= 1) {
        if (threadIdx.x < off) red[threadIdx.x] += red[threadIdx.x + off];
        __syncthreads();
    }
    if (threadIdx.x == 0) sums[blockIdx.x] = red[0];
}

// ---- B: exclusive scan of block sums (<=1024) ----
__global__ __launch_bounds__(1024) void scanB_kernel(int* __restrict__ sums, int nb) {
    __shared__ int part[1024];
    int t = threadIdx.x;
    int v = (t < nb) ? sums[t] : 0;
    part[t] = v;
    __syncthreads();
    for (int off = 1; off < 1024; off <<= 1) {
        int u = (t >= off) ? part[t - off] : 0;
        __syncthreads();
        part[t] += u;
        __syncthreads();
    }
    if (t < nb) sums[t] = part[t] - v;
}

// ---- C: apply (in-place exclusive scan) ----
__global__ __launch_bounds__(512) void scanC_kernel(int* __restrict__ a,
                                                    const int* __restrict__ sums, int M) {
    __shared__ int part[512];
    int t = threadIdx.x;
    int i = blockIdx.x * 512 + t;
    int v = (i < M) ? a[i] : 0;
    part[t] = v;
    __syncthreads();
    for (int off = 1; off < 512; off <<= 1) {
        int u = (t >= off) ? part[t - off] : 0;
        __syncthreads();
        part[t] += u;
        __syncthreads();
    }
    if (i < M) a[i] = part[t] - v + sums[blockIdx.x];
}

// ---- pass 2: partition edges into bucket runs; pack (r | local_c<<23) in 4B ----
__global__ __launch_bounds__(256) void partition_kernel(const void* __restrict__ edge,
                                                        const int* __restrict__ flag,
                                                        const int* __restrict__ offs,
                                                        unsigned int* __restrict__ pairs,
                                                        int eN, int NB, int chunk) {
    __shared__ int cur[256];
    int t = threadIdx.x, bid = blockIdx.x;
    if (t < NB) cur[t] = offs[t * B_PART + bid];
    __syncthreads();
    int f = *flag;
    int s = bid * chunk, e = min(eN, s + chunk);
    for (int i = s + t; i < e; i += 256) {
        int r = load_idx(edge, i, f);
        int c = load_idx(edge, (long long)eN + i, f);
        int slot = atomicAdd(&cur[c >> BSHIFT], 1);
        pairs[slot] = (unsigned)r | ((unsigned)(c & 511) << 23);
    }
}

// ---- pass 3: per-bucket CSR build (counting sort by lc) + WINDOW-32 degree sort ----
// order permutes only within 32-node windows (one conv block's slot range), so a
// block's fetch footprint is unchanged while its 4 waves get similar-degree octets.
__global__ __launch_bounds__(256) void bucket_fill_kernel(const unsigned int* __restrict__ pairs,
                                                          const int* __restrict__ offs,
                                                          int* __restrict__ rowptr,
                                                          float* __restrict__ dinv,
                                                          int* __restrict__ csr_src,
                                                          int* __restrict__ order,
                                                          int n, int eN, int NB) {
    __shared__ int cnt2[512];
    __shared__ int psum[256];
    __shared__ int degS[512];
    int t = threadIdx.x, b = blockIdx.x;
    int base = b << BSHIFT;
    int nLocal = min(512, n - base);
    int s = offs[b * B_PART];
    int e = (b + 1 < NB) ? offs[(b + 1) * B_PART] : eN;
    cnt2[t] = 0;
    cnt2[t + 256] = 0;
    __syncthreads();
    for (int i = s + t; i < e; i += 256) atomicAdd(&cnt2[pairs[i] >> 23], 1);
    __syncthreads();
    int a0 = cnt2[2 * t], a1 = cnt2[2 * t + 1];
    psum[t] = a0 + a1;
    __syncthreads();
    for (int off = 1; off < 256; off <<= 1) {
        int u = (t >= off) ? psum[t - off] : 0;
        __syncthreads();
        psum[t] += u;
        __syncthreads();
    }
    int ex = psum[t] - (a0 + a1);
    __syncthreads();
    cnt2[2 * t] = ex;
    cnt2[2 * t + 1] = ex + a0;
    __syncthreads();
    for (int j = t; j < nLocal; j += 256) {
        int st = cnt2[j];
        int en = (j < 511) ? cnt2[j + 1] : (e - s);
        rowptr[base + j] = s + st;
        dinv[base + j] = rsqrtf((float)(en - st + 1));
        degS[j] = en - st;
    }
    if (b == NB - 1 && t == 0) rowptr[n] = eN;
    __syncthreads();
    // ---- window-32 rank by degree (stable) ----
    for (int j = t; j < nLocal; j += 256) {
        int w0 = j & ~31;
        int wend = min(w0 + 32, nLocal);
        int d = degS[j];
        int rank = 0;
        for (int j2 = w0; j2 < wend; ++j2) {
            int d2 = degS[j2];
            rank += (d2 < d) || (d2 == d && j2 < j);
        }
        order[base + w0 + rank] = base + j;
    }
    __syncthreads();
    // ---- placement (mutates cnt2) ----
    for (int i = s + t; i < e; i += 256) {
        unsigned p = pairs[i];
        int lc = (int)(p >> 23);
        int r = (int)(p & 0x7FFFFFu);
        int slot = atomicAdd(&cnt2[lc], 1);
        csr_src[s + slot] = r;
    }
}

// ---- per-row biased-uint8 quantization of v = dinv[node]*x : qu = rint(v*127/m)+128 ----
__global__ __launch_bounds__(256) void prescale_q_kernel(const float* __restrict__ x,
                                                         const float* __restrict__ dinv,
                                                         unsigned char* __restrict__ q,
                                                         float* __restrict__ scale, int n) {
    int t = threadIdx.x;
    int k = t & 31;
    int g = blockIdx.x * 8 + (t >> 5);
    if (g >= n) return;
    float v = dinv[g] * x[(size_t)g * 32 + k];
    float m = fabsf(v);
    #pragma unroll
    for (int w = 1; w < 32; w <<= 1) m = fmaxf(m, __shfl_xor(m, w, 32));
    float inv = (m > 0.f) ? 127.f / m : 0.f;
    float qf = fminf(127.f, fmaxf(-127.f, rintf(v * inv)));
    q[(size_t)g * 32 + k] = (unsigned char)(int)(qf + 128.f);
    if (k == 0) scale[g] = m * (1.f / 127.f);
}

// Fused GCN conv, two-phase, window-degree-ordered nodes, W in LDS:
//  Phase 1 (8 lanes/node): chunk-32 upfront loads + wave-uniform subtile guards.
//  Phase 2 per wave: mini-GEMM from LDS W, residual/relu/quant.
template <int HAS_RES, int WRITE_F32, int WRITE_Q>
__global__ __launch_bounds__(256) void fused_conv_kernel(const unsigned char* __restrict__ q,
                                                         const float* __restrict__ scale,
                                                         const int* __restrict__ rowptr,
                                                         const int* __restrict__ src,
                                                         const int* __restrict__ order,
                                                         const float* __restrict__ dinv,
                                                         const float* __restrict__ W,
                                                         const float* __restrict__ bias,
                                                         const float* __restrict__ res,
                                                         float* __restrict__ out,
                                                         unsigned char* __restrict__ q_out,
                                                         float* __restrict__ scale_out,
                                                         int n) {
    __shared__ float sW[1024];
    __shared__ float aggL[32 * 36];
    int t = threadIdx.x;
    int k32 = t & 31;
    for (int i = t; i < 1024; i += 256) sW[i] = W[i];
    __syncthreads();                      // only block-wide sync (sW ready)

    // ---------- phase 1: aggregation ----------
    int slot = t >> 3;                    // node slot 0..31 (wave w owns slots 8w..8w+7)
    int m = t & 7;                        // feature quad 4m..4m+3
    int gi = blockIdx.x * 32 + slot;
    if (gi < n) {
        int g = order[gi];
        float scg = scale[g];
        unsigned qw = *(const unsigned*)(q + (size_t)g * 32 + m * 4);
        float acc0 = (float)((qw      ) & 0xFFu) * scg;
        float acc1 = (float)((qw >>  8) & 0xFFu) * scg;
        float acc2 = (float)((qw >> 16) & 0xFFu) * scg;
        float acc3 = (float)((qw >> 24)        ) * scg;
        float accs = scg;
        int s = rowptr[g], e = rowptr[g + 1];
        int last = e - 1;
        for (int p = s; p < e; p += 32) {
            int i0 = p + m;
            int sv0 = src[min(i0,      last)];
            int sv1 = src[min(i0 + 8,  last)];
            int sv2 = src[min(i0 + 16, last)];
            int sv3 = src[min(i0 + 24, last)];
            float sg0 = scale[sv0];
            float sg1 = scale[sv1];
            float sg2 = scale[sv2];
            float sg3 = scale[sv3];
            sg0 = (i0      < e) ? sg0 : 0.f;
            sg1 = (i0 + 8  < e) ? sg1 : 0.f;
            sg2 = (i0 + 16 < e) ? sg2 : 0.f;
            sg3 = (i0 + 24 < e) ? sg3 : 0.f;
            #pragma unroll
            for (int st = 0; st < 4; ++st) {
                int svx = (st == 0) ? sv0 : (st == 1) ? sv1 : (st == 2) ? sv2 : sv3;
                float sgx = (st == 0) ? sg0 : (st == 1) ? sg1 : (st == 2) ? sg2 : sg3;
                if (p + st * 8 < e) {      // wave-uniform after window degree sort
                    #pragma unroll
                    for (int jj = 0; jj < 8; ++jj) {
                        int sr = __shfl(svx, jj, 8);
                        float sc = __shfl(sgx, jj, 8);
                        unsigned w4 = *(const unsigned*)(q + (size_t)sr * 32 + m * 4);
                        acc0 = fmaf((float)((w4      ) & 0xFFu), sc, acc0);
                        acc1 = fmaf((float)((w4 >>  8) & 0xFFu), sc, acc1);
                        acc2 = fmaf((float)((w4 >> 16) & 0xFFu), sc, acc2);
                        acc3 = fmaf((float)((w4 >> 24)        ), sc, acc3);
                        accs += sc;
                    }
                }
            }
        }
        float di = dinv[g];
        float corr = 128.f * accs;
        aggL[slot * 36 + m * 4 + 0] = di * (acc0 - corr);
        aggL[slot * 36 + m * 4 + 1] = di * (acc1 - corr);
        aggL[slot * 36 + m * 4 + 2] = di * (acc2 - corr);
        aggL[slot * 36 + m * 4 + 3] = di * (acc3 - corr);
    }
    __builtin_amdgcn_wave_barrier();      // same-wave LDS ordering

    // ---------- phase 2: per-wave mini-GEMM epilogue ----------
    float bk = bias[k32];
    int wv = t >> 6;                      // wave 0..3
    int h = (t >> 5) & 1;                 // half-wave group
    #pragma unroll
    for (int r = 0; r < 4; ++r) {
        int slot2 = wv * 8 + r * 2 + h;
        int g2i = blockIdx.x * 32 + slot2;
        if (g2i < n) {
            int g2 = order[g2i];
            float agg = aggL[slot2 * 36 + k32];
            float o = bk;
            #pragma unroll
            for (int j = 0; j < 32; ++j) {
                float aj = __shfl(agg, j, 32);
                o = fmaf(aj, sW[j * 32 + k32], o);
            }
            if (HAS_RES) o += res[(size_t)g2 * 32 + k32];
            o = fmaxf(o, 0.f);
            if (WRITE_F32) out[(size_t)g2 * 32 + k32] = o;
            if (WRITE_Q) {
                float v = dinv[g2] * o;
                float mx = fabsf(v);
                #pragma unroll
                for (int w = 1; w < 32; w <<= 1) mx = fmaxf(mx, __shfl_xor(mx, w, 32));
                float inv = (mx > 0.f) ? 127.f / mx : 0.f;
                float qf = fminf(127.f, fmaxf(-127.f, rintf(v * inv)));
                q_out[(size_t)g2 * 32 + k32] = (unsigned char)(int)(qf + 128.f);
                if (k32 == 0) scale_out[g2] = mx * (1.f / 127.f);
            }
        }
    }
}

// one block per graph: mean-pool (batch is sorted -> binary search range) + 32->128 FC
__global__ __launch_bounds__(128) void pool_fc_kernel(const float* __restrict__ h,
                                                      const void* __restrict__ batch,
                                                      const int* __restrict__ flag,
                                                      const float* __restrict__ Wl,
                                                      const float* __restrict__ bl,
                                                      float* __restrict__ out, int n) {
    __shared__ float red[4][32];
    __shared__ float sp[32];
    __shared__ int srange[2];
    int g = blockIdx.x;
    int t = threadIdx.x;
    int f = *flag;
    if (t < 2) {
        int target = g + t;
        int lo = 0, hi = n;
        while (lo < hi) {
            int mid = (lo + hi) >> 1;
            int v = load_idx(batch, mid, f);
            if (v < target) lo = mid + 1; else hi = mid;
        }
        srange[t] = lo;
    }
    __syncthreads();
    int s = srange[0], e = srange[1];
    int gi = t >> 5, k = t & 31;
    float acc = 0.f;
    for (int i = s + gi; i < e; i += 4) acc += h[(size_t)i * 32 + k];
    red[gi][k] = acc;
    __syncthreads();
    if (gi == 0) {
        float v = red[0][k] + red[1][k] + red[2][k] + red[3][k];
        sp[k] = v / fmaxf((float)(e - s), 1.0f);
    }
    __syncthreads();
    float val = bl[t];
    #pragma unroll
    for (int j = 0; j < 32; ++j) val = fmaf(sp[j], Wl[j * 128 + t], val);
    out[(size_t)g * 128 + t] = val;
}

extern "C" void kernel_launch(void* const* d_in, const int* in_sizes, int n_in,
                              void* d_out, int out_size, void* d_ws, size_t ws_size,
                              hipStream_t stream) {
    const float* x = (const float*)d_in[0];
    const void* edge = d_in[1];
    const void* batch = d_in[2];
    const float* W[6] = {(const float*)d_in[3], (const float*)d_in[5],
                         (const float*)d_in[7], (const float*)d_in[9],
                         (const float*)d_in[11], (const float*)d_in[13]};
    const float* B[6] = {(const float*)d_in[4], (const float*)d_in[6],
                         (const float*)d_in[8], (const float*)d_in[10],
                         (const float*)d_in[12], (const float*)d_in[14]};
    const float* Wl = (const float*)d_in[15];
    const float* bl = (const float*)d_in[16];
    float* out = (float*)d_out;

    int n = in_sizes[0] / DIM;      // 100000 nodes
    int eN = in_sizes[1] / 2;       // 3200000 edges
    int gN = out_size / OUTD;       // 8192 graphs

    int NB = (n + 511) >> BSHIFT;   // 196 buckets (<=256 for n<=131072)
    int M = NB * B_PART;            // hist matrix size
    int chunk = (eN + B_PART - 1) / B_PART;
    int nbA = (M + 511) / 512;

    char* ws = (char*)d_ws;
    size_t off = 0;
    auto alloc = [&](size_t bytes) {
        void* p = ws + off;
        off += (bytes + 255) & ~(size_t)255;
        return p;
    };
    int* flag      = (int*)alloc(4);
    int* offs      = (int*)alloc((size_t)B_PART * 256 * 4);   // hist/offsets (bucket-major)
    int* sumsA     = (int*)alloc(1024 * 4);
    int* rowptr    = (int*)alloc((size_t)(n + 1) * 4);
    float* dinv    = (float*)alloc((size_t)n * 4);
    int* csr_src   = (int*)alloc((size_t)eN * 4);
    int* order     = (int*)alloc((size_t)n * 4);
    float* bufB    = (float*)alloc((size_t)n * DIM * 4);
    unsigned char* qX = (unsigned char*)alloc((size_t)n * DIM);
    unsigned char* qA = (unsigned char*)alloc((size_t)n * DIM);
    unsigned char* qB = (unsigned char*)alloc((size_t)n * DIM);
    unsigned char* qC = (unsigned char*)alloc((size_t)n * DIM);
    float* scX     = (float*)alloc((size_t)n * 4);
    float* scA     = (float*)alloc((size_t)n * 4);
    float* scB     = (float*)alloc((size_t)n * 4);
    float* scC     = (float*)alloc((size_t)n * 4);
    size_t pairsB  = (size_t)eN * 4;
    size_t bufCB   = (size_t)n * DIM * 4;
    void* shared0  = alloc(pairsB > bufCB ? pairsB : bufCB);  // pairs, later bufC
    unsigned int* pairs = (unsigned int*)shared0;
    float* bufC    = (float*)shared0;

    detect_dtype_kernel<<<1, 256, 0, stream>>>(edge, flag, n);
    hist_kernel<<<B_PART, 256, 0, stream>>>(edge, flag, offs, eN, NB, chunk);
    scanA_kernel<<<nbA, 512, 0, stream>>>(offs, sumsA, M);
    scanB_kernel<<<1, 1024, 0, stream>>>(sumsA, nbA);
    scanC_kernel<<<nbA, 512, 0, stream>>>(offs, sumsA, M);
    partition_kernel<<<B_PART, 256, 0, stream>>>(edge, flag, offs, pairs, eN, NB, chunk);
    bucket_fill_kernel<<<NB, 256, 0, stream>>>(pairs, offs, rowptr, dinv, csr_src, order, n, eN, NB);

    int ab8 = (n + 7) / 8;
    prescale_q_kernel<<<ab8, 256, 0, stream>>>(x, dinv, qX, scX, n);

    int ab = (n + 31) / 32;   // conv grid: 32 nodes/block

    // Res-block 1: x --(c0)--> qA --(c1)--> bufB(+qB)
    fused_conv_kernel<0, 0, 1><<<ab, 256, 0, stream>>>(qX, scX, rowptr, csr_src, order, dinv, W[0], B[0], nullptr, nullptr, qA, scA, n);
    fused_conv_kernel<1, 1, 1><<<ab, 256, 0, stream>>>(qA, scA, rowptr, csr_src, order, dinv, W[1], B[1], x,       bufB,    qB, scB, n);
    // Res-block 2: bufB --(c2)--> qA --(c3)--> bufC(+qC)   (pairs dead now)
    fused_conv_kernel<0, 0, 1><<<ab, 256, 0, stream>>>(qB, scB, rowptr, csr_src, order, dinv, W[2], B[2], nullptr, nullptr, qA, scA, n);
    fused_conv_kernel<1, 1, 1><<<ab, 256, 0, stream>>>(qA, scA, rowptr, csr_src, order, dinv, W[3], B[3], bufB,    bufC,    qC, scC, n);
    // Res-block 3: bufC --(c4)--> qA --(c5)--> bufB (final, f32 only)
    fused_conv_kernel<0, 0, 1><<<ab, 256, 0, stream>>>(qC, scC, rowptr, csr_src, order, dinv, W[4], B[4], nullptr, nullptr, qA, scA, n);
    fused_conv_kernel<1, 1, 0><<<ab, 256, 0, stream>>>(qA, scA, rowptr, csr_src, order, dinv, W[5], B[5], bufC,    bufB,    nullptr, nullptr, n);

    pool_fc_kernel<<<gN, 128, 0, stream>>>(bufB, batch, flag, Wl, bl, out, n);
}

// Round 15
// 391.751 us; speedup vs baseline: 1.2211x; 1.1137x over previous
//
#include <hip/hip_runtime.h>
#include <hip/hip_bf16.h>
#include <cstdint>

#define DIM 32
#define OUTD 128
#define B_PART 256     // blocks in hist/partition passes
#define BSHIFT 9       // bucket = 512 nodes

// ---------------- index-load helper (int32 vs int64 inputs) ----------------
__device__ __forceinline__ int load_idx(const void* p, long long i, int is64) {
    if (is64) return (int)((const long long*)p)[i];
    return ((const int*)p)[i];
}

// Detect whether integer inputs are int64 (8B) or int32 (4B).
__global__ void detect_dtype_kernel(const void* __restrict__ edge, int* __restrict__ flag, int n_nodes) {
    __shared__ int cnt;
    if (threadIdx.x == 0) cnt = 0;
    __syncthreads();
    long long v = ((const long long*)edge)[threadIdx.x];
    int ok = (v >= 0 && v < (long long)n_nodes) ? 1 : 0;
    atomicAdd(&cnt, ok);
    __syncthreads();
    if (threadIdx.x == 0) *flag = (cnt > 128) ? 1 : 0;
}

// ---- pass 1: per-(bucket, block) histogram of destination buckets ----
__global__ __launch_bounds__(256) void hist_kernel(const void* __restrict__ edge,
                                                   const int* __restrict__ flag,
                                                   int* __restrict__ histT,
                                                   int eN, int NB, int chunk) {
    __shared__ int sh[256];
    int t = threadIdx.x, bid = blockIdx.x;
    sh[t] = 0;
    __syncthreads();
    int f = *flag;
    int s = bid * chunk, e = min(eN, s + chunk);
    for (int i = s + t; i < e; i += 256) {
        int c = load_idx(edge, (long long)eN + i, f);
        atomicAdd(&sh[c >> BSHIFT], 1);
    }
    __syncthreads();
    if (t < NB) histT[t * B_PART + bid] = sh[t];   // bucket-major layout
}

// ---- generic hierarchical exclusive scan over M ints (A: block sums) ----
__global__ __launch_bounds__(512) void scanA_kernel(const int* __restrict__ a,
                                                    int* __restrict__ sums, int M) {
    __shared__ int red[512];
    int i = blockIdx.x * 512 + threadIdx.x;
    int v = (i < M) ? a[i] : 0;
    red[threadIdx.x] = v;
    __syncthreads();
    for (int off = 256; off > 0; off >>= 1) {
        if (threadIdx.x < off) red[threadIdx.x] += red[threadIdx.x + off];
        __syncthreads();
    }
    if (threadIdx.x == 0) sums[blockIdx.x] = red[0];
}

// ---- B: exclusive scan of block sums (<=1024) ----
__global__ __launch_bounds__(1024) void scanB_kernel(int* __restrict__ sums, int nb) {
    __shared__ int part[1024];
    int t = threadIdx.x;
    int v = (t < nb) ? sums[t] : 0;
    part[t] = v;
    __syncthreads();
    for (int off = 1; off < 1024; off <<= 1) {
        int u = (t >= off) ? part[t - off] : 0;
        __syncthreads();
        part[t] += u;
        __syncthreads();
    }
    if (t < nb) sums[t] = part[t] - v;
}

// ---- C: apply (in-place exclusive scan) ----
__global__ __launch_bounds__(512) void scanC_kernel(int* __restrict__ a,
                                                    const int* __restrict__ sums, int M) {
    __shared__ int part[512];
    int t = threadIdx.x;
    int i = blockIdx.x * 512 + t;
    int v = (i < M) ? a[i] : 0;
    part[t] = v;
    __syncthreads();
    for (int off = 1; off < 512; off <<= 1) {
        int u = (t >= off) ? part[t - off] : 0;
        __syncthreads();
        part[t] += u;
        __syncthreads();
    }
    if (i < M) a[i] = part[t] - v + sums[blockIdx.x];
}

// ---- pass 2: partition edges into bucket runs; pack (r | local_c<<23) in 4B ----
__global__ __launch_bounds__(256) void partition_kernel(const void* __restrict__ edge,
                                                        const int* __restrict__ flag,
                                                        const int* __restrict__ offs,
                                                        unsigned int* __restrict__ pairs,
                                                        int eN, int NB, int chunk) {
    __shared__ int cur[256];
    int t = threadIdx.x, bid = blockIdx.x;
    if (t < NB) cur[t] = offs[t * B_PART + bid];
    __syncthreads();
    int f = *flag;
    int s = bid * chunk, e = min(eN, s + chunk);
    for (int i = s + t; i < e; i += 256) {
        int r = load_idx(edge, i, f);
        int c = load_idx(edge, (long long)eN + i, f);
        int slot = atomicAdd(&cur[c >> BSHIFT], 1);
        pairs[slot] = (unsigned)r | ((unsigned)(c & 511) << 23);
    }
}

// ---- pass 3: per-bucket CSR build (counting sort by lc) + WINDOW-32 degree sort ----
__global__ __launch_bounds__(256) void bucket_fill_kernel(const unsigned int* __restrict__ pairs,
                                                          const int* __restrict__ offs,
                                                          int* __restrict__ rowptr,
                                                          float* __restrict__ dinv,
                                                          int* __restrict__ csr_src,
                                                          int* __restrict__ order,
                                                          int n, int eN, int NB) {
    __shared__ int cnt2[512];
    __shared__ int psum[256];
    __shared__ int degS[512];
    int t = threadIdx.x, b = blockIdx.x;
    int base = b << BSHIFT;
    int nLocal = min(512, n - base);
    int s = offs[b * B_PART];
    int e = (b + 1 < NB) ? offs[(b + 1) * B_PART] : eN;
    cnt2[t] = 0;
    cnt2[t + 256] = 0;
    __syncthreads();
    for (int i = s + t; i < e; i += 256) atomicAdd(&cnt2[pairs[i] >> 23], 1);
    __syncthreads();
    int a0 = cnt2[2 * t], a1 = cnt2[2 * t + 1];
    psum[t] = a0 + a1;
    __syncthreads();
    for (int off = 1; off < 256; off <<= 1) {
        int u = (t >= off) ? psum[t - off] : 0;
        __syncthreads();
        psum[t] += u;
        __syncthreads();
    }
    int ex = psum[t] - (a0 + a1);
    __syncthreads();
    cnt2[2 * t] = ex;
    cnt2[2 * t + 1] = ex + a0;
    __syncthreads();
    for (int j = t; j < nLocal; j += 256) {
        int st = cnt2[j];
        int en = (j < 511) ? cnt2[j + 1] : (e - s);
        rowptr[base + j] = s + st;
        dinv[base + j] = rsqrtf((float)(en - st + 1));
        degS[j] = en - st;
    }
    if (b == NB - 1 && t == 0) rowptr[n] = eN;
    __syncthreads();
    // ---- window-32 rank by degree (stable) ----
    for (int j = t; j < nLocal; j += 256) {
        int w0 = j & ~31;
        int wend = min(w0 + 32, nLocal);
        int d = degS[j];
        int rank = 0;
        for (int j2 = w0; j2 < wend; ++j2) {
            int d2 = degS[j2];
            rank += (d2 < d) || (d2 == d && j2 < j);
        }
        order[base + w0 + rank] = base + j;
    }
    __syncthreads();
    // ---- placement (mutates cnt2) ----
    for (int i = s + t; i < e; i += 256) {
        unsigned p = pairs[i];
        int lc = (int)(p >> 23);
        int r = (int)(p & 0x7FFFFFu);
        int slot = atomicAdd(&cnt2[lc], 1);
        csr_src[s + slot] = r;
    }
}

// ---------- 7-bit + power-of-2-exponent row codec ----------
// Row g = 8 dwords; dword m = [e:4][q(4m+3):7][q(4m+2):7][q(4m+1):7][q(4m):7]
// value = q * 2^(e-10), q in [-63,63] two's complement.
// quant_pack: all 32 lanes of a group call with their v; lanes (k&3)==0 get the
// packed dword for quad k>>2 in *outw (others' *outw undefined-but-harmless).
__device__ __forceinline__ unsigned quant_pack(float v, int k32) {
    float mx = fabsf(v);
    #pragma unroll
    for (int w = 1; w < 32; w <<= 1) mx = fmaxf(mx, __shfl_xor(mx, w, 32));
    float rm = fmaxf(mx, 1e-20f);
    int ec = (int)ceilf(log2f(rm * (1.0f / 63.0f))) + 10;
    ec = max(0, min(15, ec));
    float sinv = ldexpf(1.0f, 10 - ec);
    int qi = (int)rintf(v * sinv);
    qi = max(-63, min(63, qi));
    unsigned f = ((unsigned)(qi & 0x7F)) << (7 * (k32 & 3));
    f |= (unsigned)__shfl_xor((int)f, 1, 32);
    f |= (unsigned)__shfl_xor((int)f, 2, 32);
    return f | ((unsigned)ec << 28);
}

// ---- prescale: qp rows from x (v = dinv*x), plus the zero row at index n ----
__global__ __launch_bounds__(256) void prescale_q_kernel(const float* __restrict__ x,
                                                         const float* __restrict__ dinv,
                                                         unsigned* __restrict__ qp, int n) {
    int t = threadIdx.x;
    int k = t & 31;
    int g = blockIdx.x * 8 + (t >> 5);
    if (blockIdx.x == 0 && t < 8) qp[(size_t)n * 8 + t] = 0;   // zero row
    if (g >= n) return;
    float v = dinv[g] * x[(size_t)g * 32 + k];
    unsigned w = quant_pack(v, k);
    if ((k & 3) == 0) qp[(size_t)g * 8 + (k >> 2)] = w;
}

// Fused GCN conv, two-phase, window-degree-ordered, W in LDS, self-contained rows:
//  Phase 1 (8 lanes/node, lane m = feature quad): 1 dword gather per edge per lane;
//    decode = shift-pair sign-extend + ldexp; OOB edges -> zero row n (exact).
//  Phase 2 per wave: mini-GEMM from LDS W, residual/relu; quant re-pack if WRITE_Q.
template <int HAS_RES, int WRITE_F32, int WRITE_Q>
__global__ __launch_bounds__(256) void fused_conv_kernel(const unsigned* __restrict__ qp,
                                                         const int* __restrict__ rowptr,
                                                         const int* __restrict__ src,
                                                         const int* __restrict__ order,
                                                         const float* __restrict__ dinv,
                                                         const float* __restrict__ W,
                                                         const float* __restrict__ bias,
                                                         const float* __restrict__ res,
                                                         float* __restrict__ out,
                                                         unsigned* __restrict__ qp_out,
                                                         int n) {
    __shared__ float sW[1024];
    __shared__ float aggL[32 * 36];
    int t = threadIdx.x;
    int k32 = t & 31;
    for (int i = t; i < 1024; i += 256) sW[i] = W[i];
    if (WRITE_Q && blockIdx.x == 0 && t < 8) qp_out[(size_t)n * 8 + t] = 0;  // zero row
    __syncthreads();

    // ---------- phase 1: aggregation ----------
    int slot = t >> 3;                    // node slot 0..31 (wave w owns slots 8w..8w+7)
    int m = t & 7;                        // feature quad 4m..4m+3
    int gi = blockIdx.x * 32 + slot;
    if (gi < n) {
        int g = order[gi];
        // self term
        unsigned wس;
        unsigned ws = qp[(size_t)g * 8 + m];
        float ss = ldexpf(1.0f, (int)(ws >> 28) - 10);
        float acc0 = (float)((int)(ws << 25) >> 25) * ss;
        float acc1 = (float)((int)(ws << 18) >> 25) * ss;
        float acc2 = (float)((int)(ws << 11) >> 25) * ss;
        float acc3 = (float)((int)(ws <<  4) >> 25) * ss;
        int s = rowptr[g], e = rowptr[g + 1];
        int last = e - 1;
        for (int p = s; p < e; p += 32) {
            int i0 = p + m;
            int t0 = src[min(i0,      last)];
            int t1 = src[min(i0 + 8,  last)];
            int t2 = src[min(i0 + 16, last)];
            int t3 = src[min(i0 + 24, last)];
            int sv0 = (i0      < e) ? t0 : n;   // OOB -> zero row
            int sv1 = (i0 + 8  < e) ? t1 : n;
            int sv2 = (i0 + 16 < e) ? t2 : n;
            int sv3 = (i0 + 24 < e) ? t3 : n;
            #pragma unroll
            for (int st = 0; st < 4; ++st) {
                int svx = (st == 0) ? sv0 : (st == 1) ? sv1 : (st == 2) ? sv2 : sv3;
                if (p + st * 8 < e) {      // wave-uniform after window degree sort
                    #pragma unroll
                    for (int jj = 0; jj < 8; ++jj) {
                        int sr = __shfl(svx, jj, 8);
                        unsigned w4 = qp[(size_t)sr * 8 + m];
                        float sc = ldexpf(1.0f, (int)(w4 >> 28) - 10);
                        acc0 = fmaf((float)((int)(w4 << 25) >> 25), sc, acc0);
                        acc1 = fmaf((float)((int)(w4 << 18) >> 25), sc, acc1);
                        acc2 = fmaf((float)((int)(w4 << 11) >> 25), sc, acc2);
                        acc3 = fmaf((float)((int)(w4 <<  4) >> 25), sc, acc3);
                    }
                }
            }
        }
        float di = dinv[g];
        aggL[slot * 36 + m * 4 + 0] = di * acc0;
        aggL[slot * 36 + m * 4 + 1] = di * acc1;
        aggL[slot * 36 + m * 4 + 2] = di * acc2;
        aggL[slot * 36 + m * 4 + 3] = di * acc3;
    }
    __builtin_amdgcn_wave_barrier();      // same-wave LDS ordering

    // ---------- phase 2: per-wave mini-GEMM epilogue ----------
    float bk = bias[k32];
    int wv = t >> 6;                      // wave 0..3
    int h = (t >> 5) & 1;                 // half-wave group
    #pragma unroll
    for (int r = 0; r < 4; ++r) {
        int slot2 = wv * 8 + r * 2 + h;
        int g2i = blockIdx.x * 32 + slot2;
        if (g2i < n) {
            int g2 = order[g2i];
            float agg = aggL[slot2 * 36 + k32];
            float o = bk;
            #pragma unroll
            for (int j = 0; j < 32; ++j) {
                float aj = __shfl(agg, j, 32);
                o = fmaf(aj, sW[j * 32 + k32], o);
            }
            if (HAS_RES) o += res[(size_t)g2 * 32 + k32];
            o = fmaxf(o, 0.f);
            if (WRITE_F32) out[(size_t)g2 * 32 + k32] = o;
            if (WRITE_Q) {
                float v = dinv[g2] * o;
                unsigned w = quant_pack(v, k32);
                if ((k32 & 3) == 0) qp_out[(size_t)g2 * 8 + (k32 >> 2)] = w;
            }
        }
    }
}

// one block per graph: mean-pool (batch is sorted -> binary search range) + 32->128 FC
__global__ __launch_bounds__(128) void pool_fc_kernel(const float* __restrict__ h,
                                                      const void* __restrict__ batch,
                                                      const int* __restrict__ flag,
                                                      const float* __restrict__ Wl,
                                                      const float* __restrict__ bl,
                                                      float* __restrict__ out, int n) {
    __shared__ float red[4][32];
    __shared__ float sp[32];
    __shared__ int srange[2];
    int g = blockIdx.x;
    int t = threadIdx.x;
    int f = *flag;
    if (t < 2) {
        int target = g + t;
        int lo = 0, hi = n;
        while (lo < hi) {
            int mid = (lo + hi) >> 1;
            int v = load_idx(batch, mid, f);
            if (v < target) lo = mid + 1; else hi = mid;
        }
        srange[t] = lo;
    }
    __syncthreads();
    int s = srange[0], e = srange[1];
    int gi = t >> 5, k = t & 31;
    float acc = 0.f;
    for (int i = s + gi; i < e; i += 4) acc += h[(size_t)i * 32 + k];
    red[gi][k] = acc;
    __syncthreads();
    if (gi == 0) {
        float v = red[0][k] + red[1][k] + red[2][k] + red[3][k];
        sp[k] = v / fmaxf((float)(e - s), 1.0f);
    }
    __syncthreads();
    float val = bl[t];
    #pragma unroll
    for (int j = 0; j < 32; ++j) val = fmaf(sp[j], Wl[j * 128 + t], val);
    out[(size_t)g * 128 + t] = val;
}

extern "C" void kernel_launch(void* const* d_in, const int* in_sizes, int n_in,
                              void* d_out, int out_size, void* d_ws, size_t ws_size,
                              hipStream_t stream) {
    const float* x = (const float*)d_in[0];
    const void* edge = d_in[1];
    const void* batch = d_in[2];
    const float* W[6] = {(const float*)d_in[3], (const float*)d_in[5],
                         (const float*)d_in[7], (const float*)d_in[9],
                         (const float*)d_in[11], (const float*)d_in[13]};
    const float* B[6] = {(const float*)d_in[4], (const float*)d_in[6],
                         (const float*)d_in[8], (const float*)d_in[10],
                         (const float*)d_in[12], (const float*)d_in[14]};
    const float* Wl = (const float*)d_in[15];
    const float* bl = (const float*)d_in[16];
    float* out = (float*)d_out;

    int n = in_sizes[0] / DIM;      // 100000 nodes
    int eN = in_sizes[1] / 2;       // 3200000 edges
    int gN = out_size / OUTD;       // 8192 graphs

    int NB = (n + 511) >> BSHIFT;   // 196 buckets (<=256 for n<=131072)
    int M = NB * B_PART;            // hist matrix size
    int chunk = (eN + B_PART - 1) / B_PART;
    int nbA = (M + 511) / 512;

    char* ws = (char*)d_ws;
    size_t off = 0;
    auto alloc = [&](size_t bytes) {
        void* p = ws + off;
        off += (bytes + 255) & ~(size_t)255;
        return p;
    };
    int* flag      = (int*)alloc(4);
    int* offs      = (int*)alloc((size_t)B_PART * 256 * 4);   // hist/offsets (bucket-major)
    int* sumsA     = (int*)alloc(1024 * 4);
    int* rowptr    = (int*)alloc((size_t)(n + 1) * 4);
    float* dinv    = (float*)alloc((size_t)n * 4);
    int* csr_src   = (int*)alloc((size_t)eN * 4);
    int* order     = (int*)alloc((size_t)n * 4);
    float* bufB    = (float*)alloc((size_t)n * DIM * 4);
    unsigned* qpX  = (unsigned*)alloc((size_t)(n + 1) * 8 * 4);
    unsigned* qpA  = (unsigned*)alloc((size_t)(n + 1) * 8 * 4);
    unsigned* qpB  = (unsigned*)alloc((size_t)(n + 1) * 8 * 4);
    unsigned* qpC  = (unsigned*)alloc((size_t)(n + 1) * 8 * 4);
    size_t pairsB  = (size_t)eN * 4;
    size_t bufCB   = (size_t)n * DIM * 4;
    void* shared0  = alloc(pairsB > bufCB ? pairsB : bufCB);  // pairs, later bufC
    unsigned int* pairs = (unsigned int*)shared0;
    float* bufC    = (float*)shared0;

    detect_dtype_kernel<<<1, 256, 0, stream>>>(edge, flag, n);
    hist_kernel<<<B_PART, 256, 0, stream>>>(edge, flag, offs, eN, NB, chunk);
    scanA_kernel<<<nbA, 512, 0, stream>>>(offs, sumsA, M);
    scanB_kernel<<<1, 1024, 0, stream>>>(sumsA, nbA);
    scanC_kernel<<<nbA, 512, 0, stream>>>(offs, sumsA, M);
    partition_kernel<<<B_PART, 256, 0, stream>>>(edge, flag, offs, pairs, eN, NB, chunk);
    bucket_fill_kernel<<<NB, 256, 0, stream>>>(pairs, offs, rowptr, dinv, csr_src, order, n, eN, NB);

    int ab8 = (n + 7) / 8;
    prescale_q_kernel<<<ab8, 256, 0, stream>>>(x, dinv, qpX, n);

    int ab = (n + 31) / 32;   // conv grid: 32 nodes/block

    // Res-block 1: x --(c0)--> qpA --(c1)--> bufB(+qpB)
    fused_conv_kernel<0, 0, 1><<<ab, 256, 0, stream>>>(qpX, rowptr, csr_src, order, dinv, W[0], B[0], nullptr, nullptr, qpA, n);
    fused_conv_kernel<1, 1, 1><<<ab, 256, 0, stream>>>(qpA, rowptr, csr_src, order, dinv, W[1], B[1], x,       bufB,    qpB, n);
    // Res-block 2: bufB --(c2)--> qpA --(c3)--> bufC(+qpC)   (pairs dead now)
    fused_conv_kernel<0, 0, 1><<<ab, 256, 0, stream>>>(qpB, rowptr, csr_src, order, dinv, W[2], B[2], nullptr, nullptr, qpA, n);
    fused_conv_kernel<1, 1, 1><<<ab, 256, 0, stream>>>(qpA, rowptr, csr_src, order, dinv, W[3], B[3], bufB,    bufC,    qpC, n);
    // Res-block 3: bufC --(c4)--> qpA --(c5)--> bufB (final, f32 only)
    fused_conv_kernel<0, 0, 1><<<ab, 256, 0, stream>>>(qpC, rowptr, csr_src, order, dinv, W[4], B[4], nullptr, nullptr, qpA, n);
    fused_conv_kernel<1, 1, 0><<<ab, 256, 0, stream>>>(qpA, rowptr, csr_src, order, dinv, W[5], B[5], bufC,    bufB,    nullptr, n);

    pool_fc_kernel<<<gN, 128, 0, stream>>>(bufB, batch, flag, Wl, bl, out, n);
}

// Round 16
// 376.068 us; speedup vs baseline: 1.2721x; 1.0417x over previous
//
#include <hip/hip_runtime.h>
#include <hip/hip_bf16.h>
#include <cstdint>

#define DIM 32
#define OUTD 128
#define B_PART 256     // blocks in hist/partition passes
#define BSHIFT 9       // bucket = 512 nodes

// ---------------- index-load helper (int32 vs int64 inputs) ----------------
__device__ __forceinline__ int load_idx(const void* p, long long i, int is64) {
    if (is64) return (int)((const long long*)p)[i];
    return ((const int*)p)[i];
}

// Detect whether integer inputs are int64 (8B) or int32 (4B).
__global__ void detect_dtype_kernel(const void* __restrict__ edge, int* __restrict__ flag, int n_nodes) {
    __shared__ int cnt;
    if (threadIdx.x == 0) cnt = 0;
    __syncthreads();
    long long v = ((const long long*)edge)[threadIdx.x];
    int ok = (v >= 0 && v < (long long)n_nodes) ? 1 : 0;
    atomicAdd(&cnt, ok);
    __syncthreads();
    if (threadIdx.x == 0) *flag = (cnt > 128) ? 1 : 0;
}

// ---- pass 1: per-(bucket, block) histogram of destination buckets ----
__global__ __launch_bounds__(256) void hist_kernel(const void* __restrict__ edge,
                                                   const int* __restrict__ flag,
                                                   int* __restrict__ histT,
                                                   int eN, int NB, int chunk) {
    __shared__ int sh[256];
    int t = threadIdx.x, bid = blockIdx.x;
    sh[t] = 0;
    __syncthreads();
    int f = *flag;
    int s = bid * chunk, e = min(eN, s + chunk);
    for (int i = s + t; i < e; i += 256) {
        int c = load_idx(edge, (long long)eN + i, f);
        atomicAdd(&sh[c >> BSHIFT], 1);
    }
    __syncthreads();
    if (t < NB) histT[t * B_PART + bid] = sh[t];   // bucket-major layout
}

// ---- generic hierarchical exclusive scan over M ints (A: block sums) ----
__global__ __launch_bounds__(512) void scanA_kernel(const int* __restrict__ a,
                                                    int* __restrict__ sums, int M) {
    __shared__ int red[512];
    int i = blockIdx.x * 512 + threadIdx.x;
    int v = (i < M) ? a[i] : 0;
    red[threadIdx.x] = v;
    __syncthreads();
    for (int off = 256; off > 0; off >>= 1) {
        if (threadIdx.x < off) red[threadIdx.x] += red[threadIdx.x + off];
        __syncthreads();
    }
    if (threadIdx.x == 0) sums[blockIdx.x] = red[0];
}

// ---- B: exclusive scan of block sums (<=1024) ----
__global__ __launch_bounds__(1024) void scanB_kernel(int* __restrict__ sums, int nb) {
    __shared__ int part[1024];
    int t = threadIdx.x;
    int v = (t < nb) ? sums[t] : 0;
    part[t] = v;
    __syncthreads();
    for (int off = 1; off < 1024; off <<= 1) {
        int u = (t >= off) ? part[t - off] : 0;
        __syncthreads();
        part[t] += u;
        __syncthreads();
    }
    if (t < nb) sums[t] = part[t] - v;
}

// ---- C: apply (in-place exclusive scan) ----
__global__ __launch_bounds__(512) void scanC_kernel(int* __restrict__ a,
                                                    const int* __restrict__ sums, int M) {
    __shared__ int part[512];
    int t = threadIdx.x;
    int i = blockIdx.x * 512 + t;
    int v = (i < M) ? a[i] : 0;
    part[t] = v;
    __syncthreads();
    for (int off = 1; off < 512; off <<= 1) {
        int u = (t >= off) ? part[t - off] : 0;
        __syncthreads();
        part[t] += u;
        __syncthreads();
    }
    if (i < M) a[i] = part[t] - v + sums[blockIdx.x];
}

// ---- pass 2: partition edges into bucket runs; pack (r | local_c<<23) in 4B ----
__global__ __launch_bounds__(256) void partition_kernel(const void* __restrict__ edge,
                                                        const int* __restrict__ flag,
                                                        const int* __restrict__ offs,
                                                        unsigned int* __restrict__ pairs,
                                                        int eN, int NB, int chunk) {
    __shared__ int cur[256];
    int t = threadIdx.x, bid = blockIdx.x;
    if (t < NB) cur[t] = offs[t * B_PART + bid];
    __syncthreads();
    int f = *flag;
    int s = bid * chunk, e = min(eN, s + chunk);
    for (int i = s + t; i < e; i += 256) {
        int r = load_idx(edge, i, f);
        int c = load_idx(edge, (long long)eN + i, f);
        int slot = atomicAdd(&cur[c >> BSHIFT], 1);
        pairs[slot] = (unsigned)r | ((unsigned)(c & 511) << 23);
    }
}

// ---- pass 3: per-bucket CSR build (counting sort by lc) + WINDOW-32 degree sort ----
// 1024 threads: 16 waves/CU to hide L2-read + LDS-atomic latency (was 4 waves).
__global__ __launch_bounds__(1024) void bucket_fill_kernel(const unsigned int* __restrict__ pairs,
                                                           const int* __restrict__ offs,
                                                           int* __restrict__ rowptr,
                                                           float* __restrict__ dinv,
                                                           int* __restrict__ csr_src,
                                                           int* __restrict__ order,
                                                           int n, int eN, int NB) {
    __shared__ int cnt2[512];
    __shared__ int part[512];
    __shared__ int degS[512];
    int t = threadIdx.x, b = blockIdx.x;
    int base = b << BSHIFT;
    int nLocal = min(512, n - base);
    int s = offs[b * B_PART];
    int e = (b + 1 < NB) ? offs[(b + 1) * B_PART] : eN;
    if (t < 512) cnt2[t] = 0;
    __syncthreads();
    // count pass (stride 1024)
    for (int i = s + t; i < e; i += 1024) atomicAdd(&cnt2[pairs[i] >> 23], 1);
    __syncthreads();
    // Hillis-Steele scan over 512 counters (threads 0..511; all hit barriers)
    int v = (t < 512) ? cnt2[t] : 0;
    if (t < 512) part[t] = v;
    __syncthreads();
    for (int off = 1; off < 512; off <<= 1) {
        int u = (t < 512 && t >= off) ? part[t - off] : 0;
        __syncthreads();
        if (t < 512) part[t] += u;
        __syncthreads();
    }
    if (t < 512) cnt2[t] = part[t] - v;   // exclusive offsets
    __syncthreads();
    // rowptr + dinv + degS
    for (int j = t; j < nLocal; j += 1024) {
        int st = cnt2[j];
        int en = (j < 511) ? cnt2[j + 1] : (e - s);
        rowptr[base + j] = s + st;
        dinv[base + j] = rsqrtf((float)(en - st + 1));
        degS[j] = en - st;
    }
    if (b == NB - 1 && t == 0) rowptr[n] = eN;
    __syncthreads();
    // window-32 rank by degree (stable)
    for (int j = t; j < nLocal; j += 1024) {
        int w0 = j & ~31;
        int wend = min(w0 + 32, nLocal);
        int d = degS[j];
        int rank = 0;
        for (int j2 = w0; j2 < wend; ++j2) {
            int d2 = degS[j2];
            rank += (d2 < d) || (d2 == d && j2 < j);
        }
        order[base + w0 + rank] = base + j;
    }
    __syncthreads();
    // placement (mutates cnt2), stride 1024
    for (int i = s + t; i < e; i += 1024) {
        unsigned p = pairs[i];
        int lc = (int)(p >> 23);
        int r = (int)(p & 0x7FFFFFu);
        int slot = atomicAdd(&cnt2[lc], 1);
        csr_src[s + slot] = r;
    }
}

// ---------- 7-bit + power-of-2-exponent row codec ----------
// Row g = 8 dwords; dword m = [e:4][q(4m+3):7][q(4m+2):7][q(4m+1):7][q(4m):7]
// value = q * 2^(e-10), q in [-63,63] two's complement.
__device__ __forceinline__ unsigned quant_pack(float v, int k32) {
    float mx = fabsf(v);
    #pragma unroll
    for (int w = 1; w < 32; w <<= 1) mx = fmaxf(mx, __shfl_xor(mx, w, 32));
    float rm = fmaxf(mx, 1e-20f);
    int ec = (int)ceilf(log2f(rm * (1.0f / 63.0f))) + 10;
    ec = max(0, min(15, ec));
    float sinv = ldexpf(1.0f, 10 - ec);
    int qi = (int)rintf(v * sinv);
    qi = max(-63, min(63, qi));
    unsigned f = ((unsigned)(qi & 0x7F)) << (7 * (k32 & 3));
    f |= (unsigned)__shfl_xor((int)f, 1, 32);
    f |= (unsigned)__shfl_xor((int)f, 2, 32);
    return f | ((unsigned)ec << 28);
}

// ---- prescale: qp rows from x (v = dinv*x), plus the zero row at index n ----
__global__ __launch_bounds__(256) void prescale_q_kernel(const float* __restrict__ x,
                                                         const float* __restrict__ dinv,
                                                         unsigned* __restrict__ qp, int n) {
    int t = threadIdx.x;
    int k = t & 31;
    int g = blockIdx.x * 8 + (t >> 5);
    if (blockIdx.x == 0 && t < 8) qp[(size_t)n * 8 + t] = 0;   // zero row
    if (g >= n) return;
    float v = dinv[g] * x[(size_t)g * 32 + k];
    unsigned w = quant_pack(v, k);
    if ((k & 3) == 0) qp[(size_t)g * 8 + (k >> 2)] = w;
}

// Fused GCN conv, two-phase, window-degree-ordered, W in LDS, self-contained rows:
//  Phase 1 (8 lanes/node, lane m = feature quad): 1 dword gather per edge per lane;
//    decode = bfe sign-extend + ldexp; OOB edges -> zero row n (exact).
//  Phase 2 per wave: mini-GEMM from LDS W, residual/relu; quant re-pack if WRITE_Q.
template <int HAS_RES, int WRITE_F32, int WRITE_Q>
__global__ __launch_bounds__(256) void fused_conv_kernel(const unsigned* __restrict__ qp,
                                                         const int* __restrict__ rowptr,
                                                         const int* __restrict__ src,
                                                         const int* __restrict__ order,
                                                         const float* __restrict__ dinv,
                                                         const float* __restrict__ W,
                                                         const float* __restrict__ bias,
                                                         const float* __restrict__ res,
                                                         float* __restrict__ out,
                                                         unsigned* __restrict__ qp_out,
                                                         int n) {
    __shared__ float sW[1024];
    __shared__ float aggL[32 * 36];
    int t = threadIdx.x;
    int k32 = t & 31;
    for (int i = t; i < 1024; i += 256) sW[i] = W[i];
    if (WRITE_Q && blockIdx.x == 0 && t < 8) qp_out[(size_t)n * 8 + t] = 0;  // zero row
    __syncthreads();

    // ---------- phase 1: aggregation ----------
    int slot = t >> 3;                    // node slot 0..31 (wave w owns slots 8w..8w+7)
    int m = t & 7;                        // feature quad 4m..4m+3
    int gi = blockIdx.x * 32 + slot;
    if (gi < n) {
        int g = order[gi];
        unsigned ws = qp[(size_t)g * 8 + m];
        float ss = ldexpf(1.0f, (int)(ws >> 28) - 10);
        float acc0 = (float)((int)(ws << 25) >> 25) * ss;
        float acc1 = (float)((int)(ws << 18) >> 25) * ss;
        float acc2 = (float)((int)(ws << 11) >> 25) * ss;
        float acc3 = (float)((int)(ws <<  4) >> 25) * ss;
        int s = rowptr[g], e = rowptr[g + 1];
        int last = e - 1;
        for (int p = s; p < e; p += 32) {
            int i0 = p + m;
            int t0 = src[min(i0,      last)];
            int t1 = src[min(i0 + 8,  last)];
            int t2 = src[min(i0 + 16, last)];
            int t3 = src[min(i0 + 24, last)];
            int sv0 = (i0      < e) ? t0 : n;   // OOB -> zero row
            int sv1 = (i0 + 8  < e) ? t1 : n;
            int sv2 = (i0 + 16 < e) ? t2 : n;
            int sv3 = (i0 + 24 < e) ? t3 : n;
            #pragma unroll
            for (int st = 0; st < 4; ++st) {
                int svx = (st == 0) ? sv0 : (st == 1) ? sv1 : (st == 2) ? sv2 : sv3;
                if (p + st * 8 < e) {      // wave-uniform after window degree sort
                    #pragma unroll
                    for (int jj = 0; jj < 8; ++jj) {
                        int sr = __shfl(svx, jj, 8);
                        unsigned w4 = qp[(size_t)sr * 8 + m];
                        float sc = ldexpf(1.0f, (int)(w4 >> 28) - 10);
                        acc0 = fmaf((float)((int)(w4 << 25) >> 25), sc, acc0);
                        acc1 = fmaf((float)((int)(w4 << 18) >> 25), sc, acc1);
                        acc2 = fmaf((float)((int)(w4 << 11) >> 25), sc, acc2);
                        acc3 = fmaf((float)((int)(w4 <<  4) >> 25), sc, acc3);
                    }
                }
            }
        }
        float di = dinv[g];
        aggL[slot * 36 + m * 4 + 0] = di * acc0;
        aggL[slot * 36 + m * 4 + 1] = di * acc1;
        aggL[slot * 36 + m * 4 + 2] = di * acc2;
        aggL[slot * 36 + m * 4 + 3] = di * acc3;
    }
    __builtin_amdgcn_wave_barrier();      // same-wave LDS ordering

    // ---------- phase 2: per-wave mini-GEMM epilogue ----------
    float bk = bias[k32];
    int wv = t >> 6;                      // wave 0..3
    int h = (t >> 5) & 1;                 // half-wave group
    #pragma unroll
    for (int r = 0; r < 4; ++r) {
        int slot2 = wv * 8 + r * 2 + h;
        int g2i = blockIdx.x * 32 + slot2;
        if (g2i < n) {
            int g2 = order[g2i];
            float agg = aggL[slot2 * 36 + k32];
            float o = bk;
            #pragma unroll
            for (int j = 0; j < 32; ++j) {
                float aj = __shfl(agg, j, 32);
                o = fmaf(aj, sW[j * 32 + k32], o);
            }
            if (HAS_RES) o += res[(size_t)g2 * 32 + k32];
            o = fmaxf(o, 0.f);
            if (WRITE_F32) out[(size_t)g2 * 32 + k32] = o;
            if (WRITE_Q) {
                float v = dinv[g2] * o;
                unsigned w = quant_pack(v, k32);
                if ((k32 & 3) == 0) qp_out[(size_t)g2 * 8 + (k32 >> 2)] = w;
            }
        }
    }
}

// one block per graph: mean-pool (batch is sorted -> binary search range) + 32->128 FC
__global__ __launch_bounds__(128) void pool_fc_kernel(const float* __restrict__ h,
                                                      const void* __restrict__ batch,
                                                      const int* __restrict__ flag,
                                                      const float* __restrict__ Wl,
                                                      const float* __restrict__ bl,
                                                      float* __restrict__ out, int n) {
    __shared__ float red[4][32];
    __shared__ float sp[32];
    __shared__ int srange[2];
    int g = blockIdx.x;
    int t = threadIdx.x;
    int f = *flag;
    if (t < 2) {
        int target = g + t;
        int lo = 0, hi = n;
        while (lo < hi) {
            int mid = (lo + hi) >> 1;
            int v = load_idx(batch, mid, f);
            if (v < target) lo = mid + 1; else hi = mid;
        }
        srange[t] = lo;
    }
    __syncthreads();
    int s = srange[0], e = srange[1];
    int gi = t >> 5, k = t & 31;
    float acc = 0.f;
    for (int i = s + gi; i < e; i += 4) acc += h[(size_t)i * 32 + k];
    red[gi][k] = acc;
    __syncthreads();
    if (gi == 0) {
        float v = red[0][k] + red[1][k] + red[2][k] + red[3][k];
        sp[k] = v / fmaxf((float)(e - s), 1.0f);
    }
    __syncthreads();
    float val = bl[t];
    #pragma unroll
    for (int j = 0; j < 32; ++j) val = fmaf(sp[j], Wl[j * 128 + t], val);
    out[(size_t)g * 128 + t] = val;
}

extern "C" void kernel_launch(void* const* d_in, const int* in_sizes, int n_in,
                              void* d_out, int out_size, void* d_ws, size_t ws_size,
                              hipStream_t stream) {
    const float* x = (const float*)d_in[0];
    const void* edge = d_in[1];
    const void* batch = d_in[2];
    const float* W[6] = {(const float*)d_in[3], (const float*)d_in[5],
                         (const float*)d_in[7], (const float*)d_in[9],
                         (const float*)d_in[11], (const float*)d_in[13]};
    const float* B[6] = {(const float*)d_in[4], (const float*)d_in[6],
                         (const float*)d_in[8], (const float*)d_in[10],
                         (const float*)d_in[12], (const float*)d_in[14]};
    const float* Wl = (const float*)d_in[15];
    const float* bl = (const float*)d_in[16];
    float* out = (float*)d_out;

    int n = in_sizes[0] / DIM;      // 100000 nodes
    int eN = in_sizes[1] / 2;       // 3200000 edges
    int gN = out_size / OUTD;       // 8192 graphs

    int NB = (n + 511) >> BSHIFT;   // 196 buckets (<=256 for n<=131072)
    int M = NB * B_PART;            // hist matrix size
    int chunk = (eN + B_PART - 1) / B_PART;
    int nbA = (M + 511) / 512;

    char* ws = (char*)d_ws;
    size_t off = 0;
    auto alloc = [&](size_t bytes) {
        void* p = ws + off;
        off += (bytes + 255) & ~(size_t)255;
        return p;
    };
    int* flag      = (int*)alloc(4);
    int* offs      = (int*)alloc((size_t)B_PART * 256 * 4);   // hist/offsets (bucket-major)
    int* sumsA     = (int*)alloc(1024 * 4);
    int* rowptr    = (int*)alloc((size_t)(n + 1) * 4);
    float* dinv    = (float*)alloc((size_t)n * 4);
    int* csr_src   = (int*)alloc((size_t)eN * 4);
    int* order     = (int*)alloc((size_t)n * 4);
    float* bufB    = (float*)alloc((size_t)n * DIM * 4);
    unsigned* qpX  = (unsigned*)alloc((size_t)(n + 1) * 8 * 4);
    unsigned* qpA  = (unsigned*)alloc((size_t)(n + 1) * 8 * 4);
    unsigned* qpB  = (unsigned*)alloc((size_t)(n + 1) * 8 * 4);
    unsigned* qpC  = (unsigned*)alloc((size_t)(n + 1) * 8 * 4);
    size_t pairsB  = (size_t)eN * 4;
    size_t bufCB   = (size_t)n * DIM * 4;
    void* shared0  = alloc(pairsB > bufCB ? pairsB : bufCB);  // pairs, later bufC
    unsigned int* pairs = (unsigned int*)shared0;
    float* bufC    = (float*)shared0;

    detect_dtype_kernel<<<1, 256, 0, stream>>>(edge, flag, n);
    hist_kernel<<<B_PART, 256, 0, stream>>>(edge, flag, offs, eN, NB, chunk);
    scanA_kernel<<<nbA, 512, 0, stream>>>(offs, sumsA, M);
    scanB_kernel<<<1, 1024, 0, stream>>>(sumsA, nbA);
    scanC_kernel<<<nbA, 512, 0, stream>>>(offs, sumsA, M);
    partition_kernel<<<B_PART, 256, 0, stream>>>(edge, flag, offs, pairs, eN, NB, chunk);
    bucket_fill_kernel<<<NB, 1024, 0, stream>>>(pairs, offs, rowptr, dinv, csr_src, order, n, eN, NB);

    int ab8 = (n + 7) / 8;
    prescale_q_kernel<<<ab8, 256, 0, stream>>>(x, dinv, qpX, n);

    int ab = (n + 31) / 32;   // conv grid: 32 nodes/block

    // Res-block 1: x --(c0)--> qpA --(c1)--> bufB(+qpB)
    fused_conv_kernel<0, 0, 1><<<ab, 256, 0, stream>>>(qpX, rowptr, csr_src, order, dinv, W[0], B[0], nullptr, nullptr, qpA, n);
    fused_conv_kernel<1, 1, 1><<<ab, 256, 0, stream>>>(qpA, rowptr, csr_src, order, dinv, W[1], B[1], x,       bufB,    qpB, n);
    // Res-block 2: bufB --(c2)--> qpA --(c3)--> bufC(+qpC)   (pairs dead now)
    fused_conv_kernel<0, 0, 1><<<ab, 256, 0, stream>>>(qpB, rowptr, csr_src, order, dinv, W[2], B[2], nullptr, nullptr, qpA, n);
    fused_conv_kernel<1, 1, 1><<<ab, 256, 0, stream>>>(qpA, rowptr, csr_src, order, dinv, W[3], B[3], bufB,    bufC,    qpC, n);
    // Res-block 3: bufC --(c4)--> qpA --(c5)--> bufB (final, f32 only)
    fused_conv_kernel<0, 0, 1><<<ab, 256, 0, stream>>>(qpC, rowptr, csr_src, order, dinv, W[4], B[4], nullptr, nullptr, qpA, n);
    fused_conv_kernel<1, 1, 0><<<ab, 256, 0, stream>>>(qpA, rowptr, csr_src, order, dinv, W[5], B[5], bufC,    bufB,    nullptr, n);

    pool_fc_kernel<<<gN, 128, 0, stream>>>(bufB, batch, flag, Wl, bl, out, n);
}